// Round 2
// baseline (1644.015 us; speedup 1.0000x reference)
//
#include <hip/hip_runtime.h>
#include <math.h>

// ---------------------------------------------------------------------------
// MultiReferenceWindowAttention, all-f32.
// B_=128, T=4, M=4, N=64, C=192, nH=6, hd=32, BT=512, nW=64
// Guaranteed workspace floor (proved round 1): 177,340,416 bytes.
//   [0, 1179648)              : transposed weights (wq, wkv, wpq, wpo, wpr, wkvp)
//   qbuf  @ 1179648   (24 MB) : q  -> later qq
//   kbuf  @ +24MB     (24 MB) : k  -> later kk-chunk (fallback) -> later opo
//   vbuf  @ +48MB     (24 MB) : v  -> later vv-chunk (fallback)
//   xp    @ +72MB     (96 MB)
//   kk/vv full-size (252 MB)  : after xp only if ws_size allows (adaptive)
// d_out (24 MB) doubles as opool scratch before the final two GEMMs.
// ---------------------------------------------------------------------------

// ---- weight transpose: w (rows x 192) -> wT[c*ld + off + r] ----
__global__ void wt_kernel(const float* __restrict__ w, float* __restrict__ wT,
                          int rows, int ld, int off) {
    int i = blockIdx.x * blockDim.x + threadIdx.x;
    if (i >= rows * 192) return;
    int r = i / 192, c = i - r * 192;
    wT[c * ld + off + r] = w[i];
}

// ---- GEMM: C[row, oc] = sum_k Arow[k] * WT[k,oc] + bias[oc]
// tile 128 rows x 96 oc, K=192 in chunks of 64.
// SRC: 0 = A is a plain row-major matrix (rows x 192)
//      1 = Arow = mean_m xp[bt,m,n,:] + pos[n,:]        (bt=g>>6, n=g&63)
//      2 = seq rows: g -> (bt=c0+g/320, tok=g%320); tok<64 avg else xp slice; +pos
// EPI: 0 = plain, 1 = exact gelu, 2 = split at oc 192 -> C0/C1 (bias b0[0..384))
//      3 = split at oc 192 -> C0 (bias b0) / C1 (bias b1)
template <int SRC, int EPI>
__global__ __launch_bounds__(256, 2)
void gemm_kernel(const float* __restrict__ A, const float* __restrict__ pos,
                 const float* __restrict__ WT, const float* __restrict__ b0,
                 const float* __restrict__ b1, float* __restrict__ C0,
                 float* __restrict__ C1, int Nout, int c0)
{
    __shared__ float As[64 * 128];   // [k][row], column XOR-swizzled by (k&31)
    __shared__ float Ws[64 * 96];    // [k][oc]
    const int tid = threadIdx.x;
    const int gm0 = blockIdx.x * 128;
    const int gn0 = blockIdx.y * 96;
    const int m0 = (tid >> 4) * 8;
    const int n0 = (tid & 15) * 6;

    float acc[8][6];
#pragma unroll
    for (int i = 0; i < 8; i++)
#pragma unroll
        for (int j = 0; j < 6; j++) acc[i][j] = 0.f;

    for (int kb = 0; kb < 192; kb += 64) {
#pragma unroll
        for (int j = 0; j < 8; j++) {
            int f4 = tid + j * 256;          // 0..2047
            int r = f4 >> 4;                 // row 0..127
            int c4 = (f4 & 15) << 2;         // k 0..60
            float4 av;
            if (SRC == 0) {
                av = *reinterpret_cast<const float4*>(&A[(size_t)(gm0 + r) * 192 + kb + c4]);
            } else {
                int g = gm0 + r;
                int bt, tok;
                if (SRC == 1) { bt = g >> 6; tok = g & 63; }
                else { bt = g / 320; tok = g - bt * 320; bt += c0; }
                int n = (SRC == 2 && tok >= 64) ? (tok & 63) : tok;
                int kcol = kb + c4;
                float4 p4 = *reinterpret_cast<const float4*>(&pos[n * 192 + kcol]);
                if (SRC == 2 && tok >= 64) {
                    int mm = (tok >> 6) - 1;
                    av = *reinterpret_cast<const float4*>(
                        &A[(size_t)bt * 49152 + mm * 12288 + n * 192 + kcol]);
                } else {
                    size_t xb = (size_t)bt * 49152 + n * 192 + kcol;
                    float4 a = *reinterpret_cast<const float4*>(&A[xb]);
                    float4 b = *reinterpret_cast<const float4*>(&A[xb + 12288]);
                    float4 c = *reinterpret_cast<const float4*>(&A[xb + 24576]);
                    float4 d = *reinterpret_cast<const float4*>(&A[xb + 36864]);
                    av.x = 0.25f * (a.x + b.x + c.x + d.x);
                    av.y = 0.25f * (a.y + b.y + c.y + d.y);
                    av.z = 0.25f * (a.z + b.z + c.z + d.z);
                    av.w = 0.25f * (a.w + b.w + c.w + d.w);
                }
                av.x += p4.x; av.y += p4.y; av.z += p4.z; av.w += p4.w;
            }
            float vals[4] = {av.x, av.y, av.z, av.w};
#pragma unroll
            for (int jj = 0; jj < 4; jj++) {
                int k = c4 + jj;
                As[k * 128 + (r ^ (k & 31))] = vals[jj];
            }
        }
#pragma unroll
        for (int j = 0; j < 24; j++) {
            int f = tid + j * 256;
            int kk = f / 96;
            int nn = f - kk * 96;
            Ws[f] = WT[(size_t)(kb + kk) * Nout + gn0 + nn];
        }
        __syncthreads();

        for (int kk8 = 0; kk8 < 64; kk8 += 8) {
#pragma unroll
            for (int kk = 0; kk < 8; kk++) {
                int k = kk8 + kk;
                int colbase = m0 ^ (k & 24);
                float4 a0 = *reinterpret_cast<const float4*>(&As[k * 128 + colbase]);
                float4 a1 = *reinterpret_cast<const float4*>(&As[k * 128 + colbase + 4]);
                float av8[8] = {a0.x, a0.y, a0.z, a0.w, a1.x, a1.y, a1.z, a1.w};
                float2 w0 = *reinterpret_cast<const float2*>(&Ws[k * 96 + n0]);
                float2 w1 = *reinterpret_cast<const float2*>(&Ws[k * 96 + n0 + 2]);
                float2 w2 = *reinterpret_cast<const float2*>(&Ws[k * 96 + n0 + 4]);
                float wv[6] = {w0.x, w0.y, w1.x, w1.y, w2.x, w2.y};
#pragma unroll
                for (int j = 0; j < 8; j++) {
                    float a = av8[j];
#pragma unroll
                    for (int n = 0; n < 6; n++) acc[j ^ kk][n] += a * wv[n];
                }
            }
        }
        __syncthreads();
    }

    const bool hi = (gn0 >= 192);
    float bv[6];
#pragma unroll
    for (int n = 0; n < 6; n++) {
        int oc = gn0 + n0 + n;
        bv[n] = (EPI == 3 && hi) ? b1[oc - 192] : b0[oc];
    }
    float* dst = C0;
    int ocb = gn0 + n0;
    if ((EPI == 2 || EPI == 3) && hi) { dst = C1; ocb -= 192; }
#pragma unroll
    for (int i = 0; i < 8; i++) {
        int m = gm0 + m0 + i;
#pragma unroll
        for (int n = 0; n < 6; n++) {
            float v = acc[i][n] + bv[n];
            if (EPI == 1) v = 0.5f * v * (1.f + erff(v * 0.70710678118654752440f));
            dst[(size_t)m * 192 + ocb + n] = v;
        }
    }
}

// ---- fused window attention: block = (bb, t, m); 6 waves = 6 heads; lane = query
__global__ __launch_bounds__(384, 1)
void winattn_kernel(const float* __restrict__ qbuf, const float* __restrict__ kbuf,
                    const float* __restrict__ vbuf, const float* __restrict__ mask,
                    const float* __restrict__ rpbt, float* __restrict__ xp)
{
    __shared__ float klds[64 * 192];
    __shared__ float vlds[64 * 192];
    __shared__ float mlds[64 * 65];
    __shared__ float rlds[1350];
    const int tid = threadIdx.x;
    const int bid = blockIdx.x;       // bb*16 + t*4 + m
    const int bb = bid >> 4;
    const int t = (bid >> 2) & 3;
    const int m = bid & 3;
    const int h = tid >> 6;
    const int lane = tid & 63;

    const int kvbase = (bb * 4 + m) * 12288;
#pragma unroll
    for (int j = 0; j < 8; j++) {
        int off = (tid + j * 384) * 4;
        *reinterpret_cast<float4*>(&klds[off]) =
            *reinterpret_cast<const float4*>(&kbuf[kvbase + off]);
        *reinterpret_cast<float4*>(&vlds[off]) =
            *reinterpret_cast<const float4*>(&vbuf[kvbase + off]);
    }
    const int widx = bb & 63;
    for (int f = tid; f < 4096; f += 384)
        mlds[(f >> 6) * 65 + (f & 63)] = mask[widx * 4096 + f];
    for (int f = tid; f < 1350; f += 384) rlds[f] = rpbt[f];

    float qreg[32];
    const int qbase = ((bb * 4 + t) * 64 + lane) * 192 + h * 32;
#pragma unroll
    for (int j = 0; j < 8; j++) {
        float4 v = *reinterpret_cast<const float4*>(&qbuf[qbase + j * 4]);
        qreg[4 * j] = v.x; qreg[4 * j + 1] = v.y;
        qreg[4 * j + 2] = v.z; qreg[4 * j + 3] = v.w;
    }
    __syncthreads();

    const float scale = 0.17677669529663688110f;  // 1/sqrt(32)
    const int ni = lane >> 3, nj = lane & 7;
    float s[64];
#pragma unroll
    for (int e = 0; e < 64; e++) {
        const float4* kr = reinterpret_cast<const float4*>(&klds[e * 192 + h * 32]);
        float d0 = 0, d1 = 0, d2 = 0, d3 = 0;
#pragma unroll
        for (int q8 = 0; q8 < 8; q8++) {
            float4 k4 = kr[q8];
            d0 += qreg[q8 * 4] * k4.x;
            d1 += qreg[q8 * 4 + 1] * k4.y;
            d2 += qreg[q8 * 4 + 2] * k4.z;
            d3 += qreg[q8 * 4 + 3] * k4.w;
        }
        int ridx = (ni - (e >> 3) + 7) * 15 + (nj - (e & 7) + 7);
        s[e] = (d0 + d1 + d2 + d3) * scale + rlds[ridx * 6 + h] + mlds[lane * 65 + e];
    }
    float mx = s[0];
#pragma unroll
    for (int e = 1; e < 64; e++) mx = fmaxf(mx, s[e]);
    float l = 0.f;
#pragma unroll
    for (int e = 0; e < 64; e++) { s[e] = __expf(s[e] - mx); l += s[e]; }
    const float inv = 1.f / l;

    float o[32];
#pragma unroll
    for (int d = 0; d < 32; d++) o[d] = 0.f;
#pragma unroll
    for (int e = 0; e < 64; e++) {
        float p = s[e];
        const float4* vr = reinterpret_cast<const float4*>(&vlds[e * 192 + h * 32]);
#pragma unroll
        for (int d8 = 0; d8 < 8; d8++) {
            float4 v4 = vr[d8];
            o[d8 * 4] += p * v4.x; o[d8 * 4 + 1] += p * v4.y;
            o[d8 * 4 + 2] += p * v4.z; o[d8 * 4 + 3] += p * v4.w;
        }
    }
    const int obase = bb * 196608 + m * 49152 + t * 12288 + h * 2048 + lane * 32;
#pragma unroll
    for (int j = 0; j < 8; j++) {
        float4 v;
        v.x = o[4 * j] * inv; v.y = o[4 * j + 1] * inv;
        v.z = o[4 * j + 2] * inv; v.w = o[4 * j + 3] * inv;
        *reinterpret_cast<float4*>(&xp[obase + j * 4]) = v;
    }
}

// ---- pooling attention, projection-free: one wave per (head, bt).
// Flash over 10 key tiles of 32 tokens read from precomputed kk/vv.
__global__ __launch_bounds__(64)
void poolattn2_kernel(const float* __restrict__ kk, const float* __restrict__ vv,
                      const float* __restrict__ qq, float* __restrict__ opool, int c0)
{
    __shared__ float kls[32 * 36];   // stride 36 floats: 16B-aligned, banks spread
    __shared__ float vls[32 * 36];
    const int h = blockIdx.x;
    const int btl = blockIdx.y;
    const int bt = c0 + btl;
    const int lane = threadIdx.x;

    float qreg[32];
    const size_t qbase = ((size_t)(bt * 64 + lane)) * 192 + h * 32;
#pragma unroll
    for (int j = 0; j < 8; j++) {
        float4 v = *reinterpret_cast<const float4*>(&qq[qbase + j * 4]);
        qreg[4 * j] = v.x; qreg[4 * j + 1] = v.y;
        qreg[4 * j + 2] = v.z; qreg[4 * j + 3] = v.w;
    }
    const float scale = 0.17677669529663688110f;
    float mrun = -3.0e38f, lrun = 0.f;
    float o[32];
#pragma unroll
    for (int d = 0; d < 32; d++) o[d] = 0.f;

    for (int tt = 0; tt < 10; tt++) {
        __syncthreads();
        const float* ks = &kk[((size_t)btl * 320 + tt * 32) * 192 + h * 32];
        const float* vs = &vv[((size_t)btl * 320 + tt * 32) * 192 + h * 32];
#pragma unroll
        for (int i = 0; i < 4; i++) {
            int f4 = lane + 64 * i;          // 0..255
            int row = f4 >> 3, c4 = (f4 & 7) << 2;
            *reinterpret_cast<float4*>(&kls[row * 36 + c4]) =
                *reinterpret_cast<const float4*>(&ks[(size_t)row * 192 + c4]);
            *reinterpret_cast<float4*>(&vls[row * 36 + c4]) =
                *reinterpret_cast<const float4*>(&vs[(size_t)row * 192 + c4]);
        }
        __syncthreads();

        float s[32];
#pragma unroll
        for (int j = 0; j < 32; j++) {
            const float4* kr = reinterpret_cast<const float4*>(&kls[j * 36]);
            float d0 = 0, d1 = 0, d2 = 0, d3 = 0;
#pragma unroll
            for (int q8 = 0; q8 < 8; q8++) {
                float4 k4 = kr[q8];
                d0 += qreg[q8 * 4] * k4.x;
                d1 += qreg[q8 * 4 + 1] * k4.y;
                d2 += qreg[q8 * 4 + 2] * k4.z;
                d3 += qreg[q8 * 4 + 3] * k4.w;
            }
            s[j] = (d0 + d1 + d2 + d3) * scale;
        }
        float mt = s[0];
#pragma unroll
        for (int j = 1; j < 32; j++) mt = fmaxf(mt, s[j]);
        float mnew = fmaxf(mrun, mt);
        float fct = __expf(mrun - mnew);
        lrun *= fct;
#pragma unroll
        for (int d = 0; d < 32; d++) o[d] *= fct;
#pragma unroll
        for (int j = 0; j < 32; j++) { float p = __expf(s[j] - mnew); lrun += p; s[j] = p; }
#pragma unroll
        for (int j = 0; j < 32; j++) {
            float p = s[j];
            const float4* vr = reinterpret_cast<const float4*>(&vls[j * 36]);
#pragma unroll
            for (int d8 = 0; d8 < 8; d8++) {
                float4 v4 = vr[d8];
                o[d8 * 4] += p * v4.x; o[d8 * 4 + 1] += p * v4.y;
                o[d8 * 4 + 2] += p * v4.z; o[d8 * 4 + 3] += p * v4.w;
            }
        }
        mrun = mnew;
    }
    const float inv = 1.f / lrun;
    const size_t ob = ((size_t)(bt * 64 + lane)) * 192 + h * 32;
#pragma unroll
    for (int j = 0; j < 8; j++) {
        float4 v;
        v.x = o[4 * j] * inv; v.y = o[4 * j + 1] * inv;
        v.z = o[4 * j + 2] * inv; v.w = o[4 * j + 3] * inv;
        *reinterpret_cast<float4*>(&opool[ob + j * 4]) = v;
    }
}

extern "C" void kernel_launch(void* const* d_in, const int* in_sizes, int n_in,
                              void* d_out, int out_size, void* d_ws, size_t ws_size,
                              hipStream_t stream) {
    (void)in_sizes; (void)n_in; (void)out_size;
    const float* x      = (const float*)d_in[0];
    const float* x_kv   = (const float*)d_in[1];
    const float* mask   = (const float*)d_in[2];
    const float* rpbt   = (const float*)d_in[3];
    const float* q_w    = (const float*)d_in[4];
    const float* q_b    = (const float*)d_in[5];
    const float* kv_w   = (const float*)d_in[6];
    const float* kv_b   = (const float*)d_in[7];
    const float* pos    = (const float*)d_in[8];
    const float* pq_w   = (const float*)d_in[9];
    const float* pq_b   = (const float*)d_in[10];
    const float* pk_w   = (const float*)d_in[11];
    const float* pk_b   = (const float*)d_in[12];
    const float* pv_w   = (const float*)d_in[13];
    const float* pv_b   = (const float*)d_in[14];
    const float* po_w   = (const float*)d_in[15];
    const float* po_b   = (const float*)d_in[16];
    const float* proj_w = (const float*)d_in[17];
    const float* proj_b = (const float*)d_in[18];
    float* out = (float*)d_out;
    char* ws = (char*)d_ws;

    float* wqT   = (float*)(ws + 0);        // 192x192
    float* wkvT  = (float*)(ws + 147456);   // 192x384
    float* wpqT  = (float*)(ws + 442368);   // 192x192
    float* wpoT  = (float*)(ws + 589824);   // 192x192
    float* wprT  = (float*)(ws + 737280);   // 192x192
    float* wkvpT = (float*)(ws + 884736);   // 192x384 = [pkT | pvT]
    const size_t A0 = 1179648;
    float* qbuf = (float*)(ws + A0);
    float* kbuf = (float*)(ws + A0 + 25165824u);
    float* vbuf = (float*)(ws + A0 + 2u * 25165824u);
    float* xp   = (float*)(ws + A0 + 3u * 25165824u);
    float* qq   = qbuf;            // after winattn
    float* opo  = kbuf;            // after pooling chunks
    float* opool = out;            // d_out doubles as scratch (24 MB exactly)

    // adaptive kk/vv placement: after xp if ws allows, else overlay kbuf+vbuf
    const size_t BASE_END = 177340416ull;
    const size_t PER_BT = 2ull * 320 * 192 * 4;   // kk+vv bytes per bt = 491520
    size_t extra = ws_size > BASE_END ? ws_size - BASE_END : 0;
    int cbt; char* kkb;
    if      (extra >= 512 * PER_BT) { cbt = 512; kkb = ws + BASE_END; }
    else if (extra >= 256 * PER_BT) { cbt = 256; kkb = ws + BASE_END; }
    else if (extra >= 128 * PER_BT) { cbt = 128; kkb = ws + BASE_END; }
    else if (extra >=  64 * PER_BT) { cbt =  64; kkb = ws + BASE_END; }
    else                            { cbt =  64; kkb = (char*)kbuf; }  // 31.5MB in 48MB
    float* kkc = (float*)kkb;
    float* vvc = (float*)(kkb + (size_t)cbt * 320 * 192 * 4);

    wt_kernel<<<(192 * 192 + 255) / 256, 256, 0, stream>>>(q_w, wqT, 192, 192, 0);
    wt_kernel<<<(384 * 192 + 255) / 256, 256, 0, stream>>>(kv_w, wkvT, 384, 384, 0);
    wt_kernel<<<(192 * 192 + 255) / 256, 256, 0, stream>>>(pq_w, wpqT, 192, 192, 0);
    wt_kernel<<<(192 * 192 + 255) / 256, 256, 0, stream>>>(po_w, wpoT, 192, 192, 0);
    wt_kernel<<<(192 * 192 + 255) / 256, 256, 0, stream>>>(proj_w, wprT, 192, 192, 0);
    wt_kernel<<<(192 * 192 + 255) / 256, 256, 0, stream>>>(pk_w, wkvpT, 192, 384, 0);
    wt_kernel<<<(192 * 192 + 255) / 256, 256, 0, stream>>>(pv_w, wkvpT, 192, 384, 192);

    dim3 blk(256);
    gemm_kernel<0, 0><<<dim3(256, 2), blk, 0, stream>>>(x, nullptr, wqT, q_b, nullptr,
                                                        qbuf, nullptr, 192, 0);
    gemm_kernel<0, 2><<<dim3(256, 4), blk, 0, stream>>>(x_kv, nullptr, wkvT, kv_b, nullptr,
                                                        kbuf, vbuf, 384, 0);
    winattn_kernel<<<2048, 384, 0, stream>>>(qbuf, kbuf, vbuf, mask, rpbt, xp);
    // qq = (avg tokens + pos) @ pq^T + pq_b   (avg fused into A-staging)
    gemm_kernel<1, 0><<<dim3(256, 2), blk, 0, stream>>>(xp, pos, wpqT, pq_b, nullptr,
                                                        qq, nullptr, 192, 0);
    for (int c0 = 0; c0 < 512; c0 += cbt) {
        gemm_kernel<2, 3><<<dim3(cbt * 320 / 128, 4), blk, 0, stream>>>(
            xp, pos, wkvpT, pk_b, pv_b, kkc, vvc, 384, c0);
        poolattn2_kernel<<<dim3(6, cbt), 64, 0, stream>>>(kkc, vvc, qq, opool, c0);
    }
    // o = gelu(opool @ po^T + po_b); out = o @ proj^T + proj_b
    gemm_kernel<0, 1><<<dim3(256, 2), blk, 0, stream>>>(opool, nullptr, wpoT, po_b, nullptr,
                                                        opo, nullptr, 192, 0);
    gemm_kernel<0, 0><<<dim3(256, 2), blk, 0, stream>>>(opo, nullptr, wprT, proj_b, nullptr,
                                                        out, nullptr, 192, 0);
}

// Round 6
// 829.555 us; speedup vs baseline: 1.9818x; 1.9818x over previous
//
#include <hip/hip_runtime.h>
#include <math.h>

// ---------------------------------------------------------------------------
// MultiReferenceWindowAttention — bf16-MFMA GEMMs + f32 attention.
// B_=128, T=4, M=4, N=64, C=192, nH=6, hd=32, BT=512
// Workspace (budget = proven 177,340,416 B; we use 138.4 MB):
//   qbuf f32 @ 0        (24 MB)  q -> later qq
//   xp  bf16 @ 24 MB    (48 MB)
//   kbuf f32 @ 72 MB    (24 MB)  k -> later kk-chunk(bf16) -> later opo
//   vbuf f32 @ 96 MB    (24 MB)  v -> later (kk/vv chunk tail)
//   kk bf16 @ 72 MB (31.5 MB/chunk), vv bf16 @ ~102 MB (31.5 MB/chunk)
// d_out doubles as opool scratch (fully rewritten by final GEMM).
// ---------------------------------------------------------------------------

typedef float f32x4 __attribute__((ext_vector_type(4)));
typedef short s16x8 __attribute__((ext_vector_type(8)));
typedef unsigned short u16x4 __attribute__((ext_vector_type(4)));

__device__ __forceinline__ unsigned short f2bf(float f) {
    union { float f; unsigned u; } c; c.f = f;
    return (unsigned short)((c.u + 0x7fffu + ((c.u >> 16) & 1u)) >> 16);
}
__device__ __forceinline__ float bf2f(unsigned short h) {
    union { unsigned u; float f; } c; c.u = ((unsigned)h) << 16;
    return c.f;
}

// ---------------------------------------------------------------------------
// MFMA bf16 GEMM:  C[row, oc] = sum_k Arow[k] * W[oc][k] + bias[oc]
// Block tile 128 rows x 96 oc, K=192 staged in 2 halves of 96.
// 4 waves in 2x2 grid; wave tile 64 x 48 = 4x3 fragments of 16x16 (K=32 MFMA).
// A and W staged to LDS as bf16 [row][k] (192 B rows), 16B-chunk XOR swizzle
// by (row&3) -> conflict-spread ds_read_b128.
// SRC: 0 = A plain f32 rows; 1 = mean_m xp(bf16) + pos; 2 = seq rows from xp.
// EPI: 0 plain, 1 exact gelu, 2 split oc@192 -> C0/C1 (b0 len 384),
//      3 split oc@192 -> C0 (W0,b0) / C1 (W1,b1)
// OUTBF: 0 = f32 out, 1 = bf16 out.
// ---------------------------------------------------------------------------
template <int SRC, int EPI, int OUTBF>
__global__ __launch_bounds__(256, 3)
void mgemm_kernel(const float* __restrict__ A, const unsigned short* __restrict__ Axp,
                  const float* __restrict__ pos,
                  const float* __restrict__ W0, const float* __restrict__ W1,
                  const float* __restrict__ b0, const float* __restrict__ b1,
                  void* __restrict__ C0v, void* __restrict__ C1v, int c0)
{
    __shared__ __align__(16) char As[128 * 192];   // 24 KB bf16 [row][k(96)]
    __shared__ __align__(16) char Bs[96 * 192];    // 18 KB bf16 [oc][k(96)]
    const int tid = threadIdx.x;
    const int gm0 = blockIdx.x * 128;
    const int gn0 = blockIdx.y * 96;
    const int wid = tid >> 6;
    const int wm = wid >> 1, wn = wid & 1;
    const int lane = tid & 63;
    const int lr = lane & 15;          // fragment row (A) / col (B)
    const int lk = lane >> 4;          // k-chunk 0..3

    const bool hiN = (gn0 >= 192);
    const float* Wsel = (EPI == 3 && hiN) ? W1 : W0;
    const int wrow0 = (EPI == 3 && hiN) ? (gn0 - 192) : gn0;

    f32x4 acc[4][3];
#pragma unroll
    for (int i = 0; i < 4; i++)
#pragma unroll
        for (int j = 0; j < 3; j++) acc[i][j] = (f32x4){0.f, 0.f, 0.f, 0.f};

    for (int kb = 0; kb < 192; kb += 96) {
        // ---- stage A: 128 rows x 96 k  (3072 float4 reads -> bf16 LDS) ----
#pragma unroll
        for (int it = 0; it < 12; it++) {
            int f4 = tid + it * 256;
            int row = f4 / 24;
            int kc4 = (f4 - row * 24) * 4;      // f32 col within half
            float av[4];
            if (SRC == 0) {
                float4 v = *reinterpret_cast<const float4*>(
                    &A[(size_t)(gm0 + row) * 192 + kb + kc4]);
                av[0] = v.x; av[1] = v.y; av[2] = v.z; av[3] = v.w;
            } else {
                int g = gm0 + row;
                int bt, tok;
                if (SRC == 1) { bt = g >> 6; tok = g & 63; }
                else { bt = g / 320; tok = g - bt * 320; bt += c0; }
                int n = tok & 63;
                int kcol = kb + kc4;
                float4 p4 = *reinterpret_cast<const float4*>(&pos[n * 192 + kcol]);
                float pv[4] = {p4.x, p4.y, p4.z, p4.w};
                if (SRC == 2 && tok >= 64) {
                    int mm = (tok >> 6) - 1;
                    u16x4 a = *reinterpret_cast<const u16x4*>(
                        &Axp[(size_t)bt * 49152 + mm * 12288 + n * 192 + kcol]);
#pragma unroll
                    for (int jj = 0; jj < 4; jj++) av[jj] = bf2f(a[jj]) + pv[jj];
                } else {
                    size_t xb = (size_t)bt * 49152 + n * 192 + kcol;
                    u16x4 a0 = *reinterpret_cast<const u16x4*>(&Axp[xb]);
                    u16x4 a1 = *reinterpret_cast<const u16x4*>(&Axp[xb + 12288]);
                    u16x4 a2 = *reinterpret_cast<const u16x4*>(&Axp[xb + 24576]);
                    u16x4 a3 = *reinterpret_cast<const u16x4*>(&Axp[xb + 36864]);
#pragma unroll
                    for (int jj = 0; jj < 4; jj++)
                        av[jj] = 0.25f * (bf2f(a0[jj]) + bf2f(a1[jj]) +
                                          bf2f(a2[jj]) + bf2f(a3[jj])) + pv[jj];
                }
            }
            u16x4 bvv;
#pragma unroll
            for (int jj = 0; jj < 4; jj++) bvv[jj] = f2bf(av[jj]);
            int boff = (kc4 * 2) ^ ((row & 3) << 4);
            *reinterpret_cast<u16x4*>(As + row * 192 + boff) = bvv;
        }
        // ---- stage B: 96 oc-rows x 96 k ----
#pragma unroll
        for (int it = 0; it < 9; it++) {
            int f4 = tid + it * 256;
            int row = f4 / 24;
            int kc4 = (f4 - row * 24) * 4;
            float4 v = *reinterpret_cast<const float4*>(
                &Wsel[(size_t)(wrow0 + row) * 192 + kb + kc4]);
            u16x4 bvv;
            bvv[0] = f2bf(v.x); bvv[1] = f2bf(v.y); bvv[2] = f2bf(v.z); bvv[3] = f2bf(v.w);
            int boff = (kc4 * 2) ^ ((row & 3) << 4);
            *reinterpret_cast<u16x4*>(Bs + row * 192 + boff) = bvv;
        }
        __syncthreads();

#pragma unroll
        for (int ks = 0; ks < 3; ks++) {
            s16x8 af[4], bf[3];
#pragma unroll
            for (int i = 0; i < 4; i++) {
                int row = wm * 64 + i * 16 + lr;
                int off = (ks * 64 + lk * 16) ^ ((row & 3) << 4);
                af[i] = *reinterpret_cast<const s16x8*>(As + row * 192 + off);
            }
#pragma unroll
            for (int j = 0; j < 3; j++) {
                int row = wn * 48 + j * 16 + lr;
                int off = (ks * 64 + lk * 16) ^ ((row & 3) << 4);
                bf[j] = *reinterpret_cast<const s16x8*>(Bs + row * 192 + off);
            }
#pragma unroll
            for (int i = 0; i < 4; i++)
#pragma unroll
                for (int j = 0; j < 3; j++)
                    acc[i][j] = __builtin_amdgcn_mfma_f32_16x16x32_bf16(
                        af[i], bf[j], acc[i][j], 0, 0, 0);
        }
        __syncthreads();
    }

    // ---- epilogue: D col = l&15, row = (l>>4)*4 + r ----
#pragma unroll
    for (int j = 0; j < 3; j++) {
        int bcol = gn0 + wn * 48 + j * 16 + lr;
        float bv = (EPI == 3 && bcol >= 192) ? b1[bcol - 192] : b0[bcol];
        void* dst = C0v;
        int oc = bcol;
        if ((EPI == 2 || EPI == 3) && bcol >= 192) { dst = C1v; oc = bcol - 192; }
#pragma unroll
        for (int i = 0; i < 4; i++) {
            int rbase = gm0 + wm * 64 + i * 16 + lk * 4;
#pragma unroll
            for (int r = 0; r < 4; r++) {
                float v = acc[i][j][r] + bv;
                if (EPI == 1) v = 0.5f * v * (1.f + erff(v * 0.70710678118654752440f));
                size_t idx = (size_t)(rbase + r) * 192 + oc;
                if (OUTBF) ((unsigned short*)dst)[idx] = f2bf(v);
                else       ((float*)dst)[idx] = v;
            }
        }
    }
}

// ---- fused window attention: block = (bb, t, m); 6 waves = 6 heads; lane = query
__global__ __launch_bounds__(384, 1)
void winattn_kernel(const float* __restrict__ qbuf, const float* __restrict__ kbuf,
                    const float* __restrict__ vbuf, const float* __restrict__ mask,
                    const float* __restrict__ rpbt, unsigned short* __restrict__ xp)
{
    __shared__ float klds[64 * 192];
    __shared__ float vlds[64 * 192];
    __shared__ float mlds[64 * 65];
    __shared__ float rlds[1350];
    const int tid = threadIdx.x;
    const int bid = blockIdx.x;       // bb*16 + t*4 + m
    const int bb = bid >> 4;
    const int t = (bid >> 2) & 3;
    const int m = bid & 3;
    const int h = tid >> 6;
    const int lane = tid & 63;

    const int kvbase = (bb * 4 + m) * 12288;
#pragma unroll
    for (int j = 0; j < 8; j++) {
        int off = (tid + j * 384) * 4;
        *reinterpret_cast<float4*>(&klds[off]) =
            *reinterpret_cast<const float4*>(&kbuf[kvbase + off]);
        *reinterpret_cast<float4*>(&vlds[off]) =
            *reinterpret_cast<const float4*>(&vbuf[kvbase + off]);
    }
    const int widx = bb & 63;
    for (int f = tid; f < 4096; f += 384)
        mlds[(f >> 6) * 65 + (f & 63)] = mask[widx * 4096 + f];
    for (int f = tid; f < 1350; f += 384) rlds[f] = rpbt[f];

    float qreg[32];
    const int qbase = ((bb * 4 + t) * 64 + lane) * 192 + h * 32;
#pragma unroll
    for (int j = 0; j < 8; j++) {
        float4 v = *reinterpret_cast<const float4*>(&qbuf[qbase + j * 4]);
        qreg[4 * j] = v.x; qreg[4 * j + 1] = v.y;
        qreg[4 * j + 2] = v.z; qreg[4 * j + 3] = v.w;
    }
    __syncthreads();

    const float scale = 0.17677669529663688110f;  // 1/sqrt(32)
    const int ni = lane >> 3, nj = lane & 7;
    float s[64];
#pragma unroll
    for (int e = 0; e < 64; e++) {
        const float4* kr = reinterpret_cast<const float4*>(&klds[e * 192 + h * 32]);
        float d0 = 0, d1 = 0, d2 = 0, d3 = 0;
#pragma unroll
        for (int q8 = 0; q8 < 8; q8++) {
            float4 k4 = kr[q8];
            d0 += qreg[q8 * 4] * k4.x;
            d1 += qreg[q8 * 4 + 1] * k4.y;
            d2 += qreg[q8 * 4 + 2] * k4.z;
            d3 += qreg[q8 * 4 + 3] * k4.w;
        }
        int ridx = (ni - (e >> 3) + 7) * 15 + (nj - (e & 7) + 7);
        s[e] = (d0 + d1 + d2 + d3) * scale + rlds[ridx * 6 + h] + mlds[lane * 65 + e];
    }
    float mx = s[0];
#pragma unroll
    for (int e = 1; e < 64; e++) mx = fmaxf(mx, s[e]);
    float l = 0.f;
#pragma unroll
    for (int e = 0; e < 64; e++) { s[e] = __expf(s[e] - mx); l += s[e]; }
    const float inv = 1.f / l;

    float o[32];
#pragma unroll
    for (int d = 0; d < 32; d++) o[d] = 0.f;
#pragma unroll
    for (int e = 0; e < 64; e++) {
        float p = s[e];
        const float4* vr = reinterpret_cast<const float4*>(&vlds[e * 192 + h * 32]);
#pragma unroll
        for (int d8 = 0; d8 < 8; d8++) {
            float4 v4 = vr[d8];
            o[d8 * 4] += p * v4.x; o[d8 * 4 + 1] += p * v4.y;
            o[d8 * 4 + 2] += p * v4.z; o[d8 * 4 + 3] += p * v4.w;
        }
    }
    // faithful-torch flat xp layout (verified rounds 1-2), now bf16
    const int obase = bb * 196608 + m * 49152 + t * 12288 + h * 2048 + lane * 32;
#pragma unroll
    for (int j = 0; j < 8; j++) {
        u16x4 v;
        v[0] = f2bf(o[4 * j] * inv); v[1] = f2bf(o[4 * j + 1] * inv);
        v[2] = f2bf(o[4 * j + 2] * inv); v[3] = f2bf(o[4 * j + 3] * inv);
        *reinterpret_cast<u16x4*>(&xp[obase + j * 4]) = v;
    }
}

// ---------------------------------------------------------------------------
// Pooling attention: block = (h, btl), 320 threads = 5 waves.
// Wave w handles key tiles {w, w+5} of 10 (32 keys each) with private online
// softmax; partials merged via LDS. K/V head-slices staged bf16->f32 in LDS.
// ---------------------------------------------------------------------------
__global__ __launch_bounds__(320)
void poolattn3_kernel(const unsigned short* __restrict__ kk,
                      const unsigned short* __restrict__ vv,
                      const float* __restrict__ qq, float* __restrict__ opool, int c0)
{
    __shared__ float ubuf[10560];      // union: K/V slots (w*2048) | sco (w*2112+q*33+d)
    __shared__ float scm[320], scl[320];
    const int tid = threadIdx.x;
    const int w = tid >> 6, lane = tid & 63;
    const int h = blockIdx.x, btl = blockIdx.y;
    const int bt = c0 + btl;
    float* Kf = ubuf + w * 2048;
    float* Vf = Kf + 1024;

    float qreg[32];
    const size_t qbase = (size_t)(bt * 64 + lane) * 192 + h * 32;
#pragma unroll
    for (int j = 0; j < 8; j++) {
        float4 v = *reinterpret_cast<const float4*>(&qq[qbase + j * 4]);
        qreg[4 * j] = v.x; qreg[4 * j + 1] = v.y;
        qreg[4 * j + 2] = v.z; qreg[4 * j + 3] = v.w;
    }
    const float scale = 0.17677669529663688110f;
    float mrun = -3.0e38f, lrun = 0.f;
    float o[32];
#pragma unroll
    for (int d = 0; d < 32; d++) o[d] = 0.f;

#pragma unroll
    for (int it = 0; it < 2; it++) {
        const int tt = w + it * 5;
        const unsigned short* ks = kk + (size_t)(btl * 320 + tt * 32) * 192 + h * 32;
        const unsigned short* vs = vv + (size_t)(btl * 320 + tt * 32) * 192 + h * 32;
#pragma unroll
        for (int ci = 0; ci < 2; ci++) {
            int idx = lane + ci * 64;          // 0..127
            int j = idx >> 2, q4 = (idx & 3) * 8;
            s16x8 kv8 = *reinterpret_cast<const s16x8*>(&ks[j * 192 + q4]);
            s16x8 vv8 = *reinterpret_cast<const s16x8*>(&vs[j * 192 + q4]);
            f32x4 lo, hi, vlo, vhi;
#pragma unroll
            for (int e = 0; e < 4; e++) {
                lo[e] = bf2f((unsigned short)kv8[e]);
                hi[e] = bf2f((unsigned short)kv8[e + 4]);
                vlo[e] = bf2f((unsigned short)vv8[e]);
                vhi[e] = bf2f((unsigned short)vv8[e + 4]);
            }
            *reinterpret_cast<f32x4*>(Kf + j * 32 + q4) = lo;
            *reinterpret_cast<f32x4*>(Kf + j * 32 + q4 + 4) = hi;
            *reinterpret_cast<f32x4*>(Vf + j * 32 + q4) = vlo;
            *reinterpret_cast<f32x4*>(Vf + j * 32 + q4 + 4) = vhi;
        }
        // same-wave LDS dependency: compiler inserts lgkmcnt wait
        float s[32];
#pragma unroll
        for (int j = 0; j < 32; j++) {
            const float4* kr = reinterpret_cast<const float4*>(Kf + j * 32);
            float d0 = 0, d1 = 0, d2 = 0, d3 = 0;
#pragma unroll
            for (int q8 = 0; q8 < 8; q8++) {
                float4 k4 = kr[q8];
                d0 += qreg[q8 * 4] * k4.x;
                d1 += qreg[q8 * 4 + 1] * k4.y;
                d2 += qreg[q8 * 4 + 2] * k4.z;
                d3 += qreg[q8 * 4 + 3] * k4.w;
            }
            s[j] = (d0 + d1 + d2 + d3) * scale;
        }
        float mt = s[0];
#pragma unroll
        for (int j = 1; j < 32; j++) mt = fmaxf(mt, s[j]);
        float mnew = fmaxf(mrun, mt);
        float fct = __expf(mrun - mnew);
        lrun *= fct;
#pragma unroll
        for (int d = 0; d < 32; d++) o[d] *= fct;
#pragma unroll
        for (int j = 0; j < 32; j++) { float p = __expf(s[j] - mnew); lrun += p; s[j] = p; }
#pragma unroll
        for (int j = 0; j < 32; j++) {
            float p = s[j];
            const float4* vr = reinterpret_cast<const float4*>(Vf + j * 32);
#pragma unroll
            for (int d8 = 0; d8 < 8; d8++) {
                float4 v4 = vr[d8];
                o[d8 * 4] += p * v4.x; o[d8 * 4 + 1] += p * v4.y;
                o[d8 * 4 + 2] += p * v4.z; o[d8 * 4 + 3] += p * v4.w;
            }
        }
        mrun = mnew;
    }
    __syncthreads();                 // everyone done with K/V region
    scm[w * 64 + lane] = mrun;
    scl[w * 64 + lane] = lrun;
#pragma unroll
    for (int d = 0; d < 32; d++) ubuf[w * 2112 + lane * 33 + d] = o[d];
    __syncthreads();

    if (w == 0) {
        float m5 = scm[lane];
#pragma unroll
        for (int ww = 1; ww < 5; ww++) m5 = fmaxf(m5, scm[ww * 64 + lane]);
        float den = 0.f;
        float od[32];
#pragma unroll
        for (int d = 0; d < 32; d++) od[d] = 0.f;
#pragma unroll
        for (int ww = 0; ww < 5; ww++) {
            float f = __expf(scm[ww * 64 + lane] - m5);
            den += f * scl[ww * 64 + lane];
            const float* src = ubuf + ww * 2112 + lane * 33;
#pragma unroll
            for (int d = 0; d < 32; d++) od[d] += f * src[d];
        }
        const float inv = 1.f / den;
        const size_t ob = (size_t)(bt * 64 + lane) * 192 + h * 32;
#pragma unroll
        for (int j = 0; j < 8; j++) {
            float4 v;
            v.x = od[4 * j] * inv; v.y = od[4 * j + 1] * inv;
            v.z = od[4 * j + 2] * inv; v.w = od[4 * j + 3] * inv;
            *reinterpret_cast<float4*>(&opool[ob + j * 4]) = v;
        }
    }
}

extern "C" void kernel_launch(void* const* d_in, const int* in_sizes, int n_in,
                              void* d_out, int out_size, void* d_ws, size_t ws_size,
                              hipStream_t stream) {
    (void)in_sizes; (void)n_in; (void)out_size; (void)ws_size;
    const float* x      = (const float*)d_in[0];
    const float* x_kv   = (const float*)d_in[1];
    const float* mask   = (const float*)d_in[2];
    const float* rpbt   = (const float*)d_in[3];
    const float* q_w    = (const float*)d_in[4];
    const float* q_b    = (const float*)d_in[5];
    const float* kv_w   = (const float*)d_in[6];
    const float* kv_b   = (const float*)d_in[7];
    const float* pos    = (const float*)d_in[8];
    const float* pq_w   = (const float*)d_in[9];
    const float* pq_b   = (const float*)d_in[10];
    const float* pk_w   = (const float*)d_in[11];
    const float* pk_b   = (const float*)d_in[12];
    const float* pv_w   = (const float*)d_in[13];
    const float* pv_b   = (const float*)d_in[14];
    const float* po_w   = (const float*)d_in[15];
    const float* po_b   = (const float*)d_in[16];
    const float* proj_w = (const float*)d_in[17];
    const float* proj_b = (const float*)d_in[18];
    float* out = (float*)d_out;
    char* ws = (char*)d_ws;

    float*          qbuf = (float*)(ws);                      // 24 MB
    unsigned short* xp   = (unsigned short*)(ws + 25165824u); // 48 MB bf16
    float*          kbuf = (float*)(ws + 75497472u);          // 24 MB
    float*          vbuf = (float*)(ws + 100663296u);         // 24 MB
    float*          qq   = qbuf;
    unsigned short* kkc  = (unsigned short*)(ws + 75497472u);  // 31.5 MB / chunk
    unsigned short* vvc  = (unsigned short*)(ws + 106954752u); // 31.5 MB / chunk
    float*          opo  = (float*)(ws + 75497472u);           // after pooling
    float*          opool = out;                               // d_out as scratch

    dim3 blk(256);
    // q = x @ q_w^T + q_b
    mgemm_kernel<0, 0, 0><<<dim3(256, 2), blk, 0, stream>>>(
        x, nullptr, nullptr, q_w, nullptr, q_b, nullptr, qbuf, nullptr, 0);
    // k,v = x_kv @ kv_w^T + kv_b  (split at oc 192)
    mgemm_kernel<0, 2, 0><<<dim3(256, 4), blk, 0, stream>>>(
        x_kv, nullptr, nullptr, kv_w, nullptr, kv_b, nullptr, kbuf, vbuf, 0);
    winattn_kernel<<<2048, 384, 0, stream>>>(qbuf, kbuf, vbuf, mask, rpbt, xp);
    // qq = (mean_m xp + pos) @ pq_w^T + pq_b
    mgemm_kernel<1, 0, 0><<<dim3(256, 2), blk, 0, stream>>>(
        nullptr, xp, pos, pq_w, nullptr, pq_b, nullptr, qq, nullptr, 0);
    // pooling in 2 chunks of 256 bt
    for (int c0 = 0; c0 < 512; c0 += 256) {
        mgemm_kernel<2, 3, 1><<<dim3(640, 4), blk, 0, stream>>>(
            nullptr, xp, pos, pk_w, pv_w, pk_b, pv_b, kkc, vvc, c0);
        poolattn3_kernel<<<dim3(6, 256), 320, 0, stream>>>(kkc, vvc, qq, opool, c0);
    }
    // opo = gelu(opool @ po_w^T + po_b); out = opo @ proj_w^T + proj_b
    mgemm_kernel<0, 1, 0><<<dim3(256, 2), blk, 0, stream>>>(
        opool, nullptr, nullptr, po_w, nullptr, po_b, nullptr, opo, nullptr, 0);
    mgemm_kernel<0, 0, 0><<<dim3(256, 2), blk, 0, stream>>>(
        opo, nullptr, nullptr, proj_w, nullptr, proj_b, nullptr, out, nullptr, 0);
}

// Round 7
// 796.263 us; speedup vs baseline: 2.0647x; 1.0418x over previous
//
#include <hip/hip_runtime.h>
#include <math.h>

// ---------------------------------------------------------------------------
// MultiReferenceWindowAttention — bf16-MFMA GEMMs + f32 attention.
// B_=128, T=4, M=4, N=64, C=192, nH=6, hd=32, BT=512
// Workspace (<= proven 177,340,416 B):
//   qbuf f32  @ 0      (24 MB)  q -> later qq
//   xp  bf16  @ 24 MB  (48 MB)
//   kbuf bf16 @ 72 MB  (12 MB)  k -> later kk-chunk(bf16) -> later opo
//   vbuf bf16 @ 84 MB  (12 MB)  v
//   kk bf16 @ 72 MB (31.5 MB/chunk), vv bf16 @ 102 MB (31.5 MB/chunk)
// d_out doubles as opool scratch (fully rewritten by final GEMM).
// ---------------------------------------------------------------------------

typedef float f32x4 __attribute__((ext_vector_type(4)));
typedef short s16x8 __attribute__((ext_vector_type(8)));
typedef unsigned short u16x4 __attribute__((ext_vector_type(4)));

__device__ __forceinline__ unsigned short f2bf(float f) {
    union { float f; unsigned u; } c; c.f = f;
    return (unsigned short)((c.u + 0x7fffu + ((c.u >> 16) & 1u)) >> 16);
}
__device__ __forceinline__ float bf2f(unsigned short h) {
    union { unsigned u; float f; } c; c.u = ((unsigned)h) << 16;
    return c.f;
}

// ---------------------------------------------------------------------------
// MFMA bf16 GEMM:  C[row, oc] = sum_k Arow[k] * W[oc][k] + bias[oc]
// Block tile 128 rows x 96 oc, K=192 staged in 2 halves of 96.
// 4 waves in 2x2 grid; wave tile 64 x 48 = 4x3 fragments of 16x16 (K=32 MFMA).
// SRC: 0 = A plain f32 rows; 1 = mean_m xp(bf16) + pos; 2 = seq rows from xp.
// EPI: 0 plain, 1 exact gelu, 2 split oc@192 -> C0/C1 (b0 len 384),
//      3 split oc@192 -> C0 (W0,b0) / C1 (W1,b1)
// OUTBF: 0 = f32 out, 1 = bf16 out.
// ---------------------------------------------------------------------------
template <int SRC, int EPI, int OUTBF>
__global__ __launch_bounds__(256, 3)
void mgemm_kernel(const float* __restrict__ A, const unsigned short* __restrict__ Axp,
                  const float* __restrict__ pos,
                  const float* __restrict__ W0, const float* __restrict__ W1,
                  const float* __restrict__ b0, const float* __restrict__ b1,
                  void* __restrict__ C0v, void* __restrict__ C1v, int c0)
{
    __shared__ __align__(16) char As[128 * 192];   // 24 KB bf16 [row][k(96)]
    __shared__ __align__(16) char Bs[96 * 192];    // 18 KB bf16 [oc][k(96)]
    const int tid = threadIdx.x;
    const int gm0 = blockIdx.x * 128;
    const int gn0 = blockIdx.y * 96;
    const int wid = tid >> 6;
    const int wm = wid >> 1, wn = wid & 1;
    const int lane = tid & 63;
    const int lr = lane & 15;          // fragment row (A) / col (B)
    const int lk = lane >> 4;          // k-chunk 0..3

    const bool hiN = (gn0 >= 192);
    const float* Wsel = (EPI == 3 && hiN) ? W1 : W0;
    const int wrow0 = (EPI == 3 && hiN) ? (gn0 - 192) : gn0;

    f32x4 acc[4][3];
#pragma unroll
    for (int i = 0; i < 4; i++)
#pragma unroll
        for (int j = 0; j < 3; j++) acc[i][j] = (f32x4){0.f, 0.f, 0.f, 0.f};

    for (int kb = 0; kb < 192; kb += 96) {
        // ---- stage A: 128 rows x 96 k ----
#pragma unroll
        for (int it = 0; it < 12; it++) {
            int f4 = tid + it * 256;
            int row = f4 / 24;
            int kc4 = (f4 - row * 24) * 4;      // f32 col within half
            float av[4];
            if (SRC == 0) {
                float4 v = *reinterpret_cast<const float4*>(
                    &A[(size_t)(gm0 + row) * 192 + kb + kc4]);
                av[0] = v.x; av[1] = v.y; av[2] = v.z; av[3] = v.w;
            } else {
                int g = gm0 + row;
                int bt, tok;
                if (SRC == 1) { bt = g >> 6; tok = g & 63; }
                else { bt = g / 320; tok = g - bt * 320; bt += c0; }
                int n = tok & 63;
                int kcol = kb + kc4;
                float4 p4 = *reinterpret_cast<const float4*>(&pos[n * 192 + kcol]);
                float pv[4] = {p4.x, p4.y, p4.z, p4.w};
                if (SRC == 2 && tok >= 64) {
                    int mm = (tok >> 6) - 1;
                    u16x4 a = *reinterpret_cast<const u16x4*>(
                        &Axp[(size_t)bt * 49152 + mm * 12288 + n * 192 + kcol]);
#pragma unroll
                    for (int jj = 0; jj < 4; jj++) av[jj] = bf2f(a[jj]) + pv[jj];
                } else {
                    size_t xb = (size_t)bt * 49152 + n * 192 + kcol;
                    u16x4 a0 = *reinterpret_cast<const u16x4*>(&Axp[xb]);
                    u16x4 a1 = *reinterpret_cast<const u16x4*>(&Axp[xb + 12288]);
                    u16x4 a2 = *reinterpret_cast<const u16x4*>(&Axp[xb + 24576]);
                    u16x4 a3 = *reinterpret_cast<const u16x4*>(&Axp[xb + 36864]);
#pragma unroll
                    for (int jj = 0; jj < 4; jj++)
                        av[jj] = 0.25f * (bf2f(a0[jj]) + bf2f(a1[jj]) +
                                          bf2f(a2[jj]) + bf2f(a3[jj])) + pv[jj];
                }
            }
            u16x4 bvv;
#pragma unroll
            for (int jj = 0; jj < 4; jj++) bvv[jj] = f2bf(av[jj]);
            int boff = (kc4 * 2) ^ ((row & 3) << 4);
            *reinterpret_cast<u16x4*>(As + row * 192 + boff) = bvv;
        }
        // ---- stage B: 96 oc-rows x 96 k ----
#pragma unroll
        for (int it = 0; it < 9; it++) {
            int f4 = tid + it * 256;
            int row = f4 / 24;
            int kc4 = (f4 - row * 24) * 4;
            float4 v = *reinterpret_cast<const float4*>(
                &Wsel[(size_t)(wrow0 + row) * 192 + kb + kc4]);
            u16x4 bvv;
            bvv[0] = f2bf(v.x); bvv[1] = f2bf(v.y); bvv[2] = f2bf(v.z); bvv[3] = f2bf(v.w);
            int boff = (kc4 * 2) ^ ((row & 3) << 4);
            *reinterpret_cast<u16x4*>(Bs + row * 192 + boff) = bvv;
        }
        __syncthreads();

#pragma unroll
        for (int ks = 0; ks < 3; ks++) {
            s16x8 af[4], bf[3];
#pragma unroll
            for (int i = 0; i < 4; i++) {
                int row = wm * 64 + i * 16 + lr;
                int off = (ks * 64 + lk * 16) ^ ((row & 3) << 4);
                af[i] = *reinterpret_cast<const s16x8*>(As + row * 192 + off);
            }
#pragma unroll
            for (int j = 0; j < 3; j++) {
                int row = wn * 48 + j * 16 + lr;
                int off = (ks * 64 + lk * 16) ^ ((row & 3) << 4);
                bf[j] = *reinterpret_cast<const s16x8*>(Bs + row * 192 + off);
            }
#pragma unroll
            for (int i = 0; i < 4; i++)
#pragma unroll
                for (int j = 0; j < 3; j++)
                    acc[i][j] = __builtin_amdgcn_mfma_f32_16x16x32_bf16(
                        af[i], bf[j], acc[i][j], 0, 0, 0);
        }
        __syncthreads();
    }

    // ---- epilogue: D col = l&15, row = (l>>4)*4 + r ----
#pragma unroll
    for (int j = 0; j < 3; j++) {
        int bcol = gn0 + wn * 48 + j * 16 + lr;
        float bv = (EPI == 3 && bcol >= 192) ? b1[bcol - 192] : b0[bcol];
        void* dst = C0v;
        int oc = bcol;
        if ((EPI == 2 || EPI == 3) && bcol >= 192) { dst = C1v; oc = bcol - 192; }
#pragma unroll
        for (int i = 0; i < 4; i++) {
            int rbase = gm0 + wm * 64 + i * 16 + lk * 4;
#pragma unroll
            for (int r = 0; r < 4; r++) {
                float v = acc[i][j][r] + bv;
                if (EPI == 1) v = 0.5f * v * (1.f + erff(v * 0.70710678118654752440f));
                size_t idx = (size_t)(rbase + r) * 192 + oc;
                if (OUTBF) ((unsigned short*)dst)[idx] = f2bf(v);
                else       ((float*)dst)[idx] = v;
            }
        }
    }
}

// ---------------------------------------------------------------------------
// Fused window attention, key-split: block = (bb, t, m), 768 threads = 12
// waves. Wave w: head h = w>>1, keys [(w&1)*32, (w&1)*32+32). Private online
// softmax per wave; pair-merge via LDS (odd wave passes bf16-packed scaled o).
// K/V arrive bf16, staged to f32 LDS. rpb stored transposed [h][ridx] to
// kill the ~8-way bank conflicts of [ridx][h].
// ---------------------------------------------------------------------------
__global__ __launch_bounds__(768, 1)
void winattn_kernel(const float* __restrict__ qbuf,
                    const unsigned short* __restrict__ kbuf,
                    const unsigned short* __restrict__ vbuf,
                    const float* __restrict__ mask,
                    const float* __restrict__ rpbt, unsigned short* __restrict__ xp)
{
    __shared__ float klds[64 * 192];       // 48 KB
    __shared__ float vlds[64 * 192];       // 48 KB
    __shared__ float mlds[64 * 65];        // 16.25 KB
    __shared__ float rldsT[6 * 225];       // 5.3 KB  [h][ridx]
    __shared__ float exm[768];             // 3 KB
    __shared__ float exl[768];             // 3 KB
    __shared__ unsigned obuf[6 * 64 * 17]; // 25.5 KB (u32 = 2 packed bf16)
    const int tid = threadIdx.x;
    const int bid = blockIdx.x;            // bb*16 + t*4 + m
    const int bb = bid >> 4;
    const int t = (bid >> 2) & 3;
    const int m = bid & 3;
    const int w = tid >> 6;
    const int h = w >> 1;
    const int lane = tid & 63;

    const int kvbase = (bb * 4 + m) * 12288;
#pragma unroll
    for (int it = 0; it < 4; it++) {
        int c4 = tid + it * 768;           // 0..3071 quads of 4 elems
        int off = c4 * 4;
        u16x4 kq = *reinterpret_cast<const u16x4*>(&kbuf[kvbase + off]);
        u16x4 vq = *reinterpret_cast<const u16x4*>(&vbuf[kvbase + off]);
        f32x4 kf, vf;
#pragma unroll
        for (int e = 0; e < 4; e++) { kf[e] = bf2f(kq[e]); vf[e] = bf2f(vq[e]); }
        *reinterpret_cast<f32x4*>(&klds[off]) = kf;
        *reinterpret_cast<f32x4*>(&vlds[off]) = vf;
    }
    const int widx = bb & 63;
    for (int f = tid; f < 4096; f += 768)
        mlds[(f >> 6) * 65 + (f & 63)] = mask[widx * 4096 + f];
    for (int f = tid; f < 1350; f += 768) {
        int hh = f / 225, rr = f - hh * 225;
        rldsT[f] = rpbt[rr * 6 + hh];
    }

    float qreg[32];
    const int qbase = ((bb * 4 + t) * 64 + lane) * 192 + h * 32;
#pragma unroll
    for (int j = 0; j < 8; j++) {
        float4 v = *reinterpret_cast<const float4*>(&qbuf[qbase + j * 4]);
        qreg[4 * j] = v.x; qreg[4 * j + 1] = v.y;
        qreg[4 * j + 2] = v.z; qreg[4 * j + 3] = v.w;
    }
    __syncthreads();

    const float scale = 0.17677669529663688110f;  // 1/sqrt(32)
    const int ni = lane >> 3, nj = lane & 7;
    const int e0 = (w & 1) << 5;
    float s[32];
#pragma unroll
    for (int ee = 0; ee < 32; ee++) {
        int e = e0 + ee;
        const float4* kr = reinterpret_cast<const float4*>(&klds[e * 192 + h * 32]);
        float d0 = 0, d1 = 0, d2 = 0, d3 = 0;
#pragma unroll
        for (int q8 = 0; q8 < 8; q8++) {
            float4 k4 = kr[q8];
            d0 += qreg[q8 * 4] * k4.x;
            d1 += qreg[q8 * 4 + 1] * k4.y;
            d2 += qreg[q8 * 4 + 2] * k4.z;
            d3 += qreg[q8 * 4 + 3] * k4.w;
        }
        int ridx = (ni - (e >> 3) + 7) * 15 + (nj - (e & 7) + 7);
        s[ee] = (d0 + d1 + d2 + d3) * scale + rldsT[h * 225 + ridx] + mlds[lane * 65 + e];
    }
    float mrun = s[0];
#pragma unroll
    for (int ee = 1; ee < 32; ee++) mrun = fmaxf(mrun, s[ee]);
    float lrun = 0.f;
#pragma unroll
    for (int ee = 0; ee < 32; ee++) { s[ee] = __expf(s[ee] - mrun); lrun += s[ee]; }

    float o[32];
#pragma unroll
    for (int d = 0; d < 32; d++) o[d] = 0.f;
#pragma unroll
    for (int ee = 0; ee < 32; ee++) {
        float p = s[ee];
        const float4* vr = reinterpret_cast<const float4*>(&vlds[(e0 + ee) * 192 + h * 32]);
#pragma unroll
        for (int d8 = 0; d8 < 8; d8++) {
            float4 v4 = vr[d8];
            o[d8 * 4] += p * v4.x; o[d8 * 4 + 1] += p * v4.y;
            o[d8 * 4 + 2] += p * v4.z; o[d8 * 4 + 3] += p * v4.w;
        }
    }

    // ---- pair merge: waves (2h, 2h+1) ----
    __syncthreads();
    exm[w * 64 + lane] = mrun;
    __syncthreads();
    float mo = exm[(w ^ 1) * 64 + lane];
    float mt = fmaxf(mrun, mo);
    float fs = __expf(mrun - mt);
    if (w & 1) {
        unsigned* ob = &obuf[h * 1088 + lane * 17];
#pragma unroll
        for (int j = 0; j < 16; j++) {
            unsigned lo = f2bf(fs * o[2 * j]);
            unsigned hi = f2bf(fs * o[2 * j + 1]);
            ob[j] = lo | (hi << 16);
        }
        exl[w * 64 + lane] = fs * lrun;
    }
    __syncthreads();
    if (!(w & 1)) {
        float lt = fs * lrun + exl[(w + 1) * 64 + lane];
        const float inv = 1.f / lt;
        const unsigned* ob = &obuf[h * 1088 + lane * 17];
        const int obase = bb * 196608 + m * 49152 + t * 12288 + h * 2048 + lane * 32;
#pragma unroll
        for (int j = 0; j < 8; j++) {
            unsigned p0 = ob[2 * j], p1 = ob[2 * j + 1];
            u16x4 v;
            v[0] = f2bf((fs * o[4 * j]     + bf2f((unsigned short)(p0 & 0xffff))) * inv);
            v[1] = f2bf((fs * o[4 * j + 1] + bf2f((unsigned short)(p0 >> 16))) * inv);
            v[2] = f2bf((fs * o[4 * j + 2] + bf2f((unsigned short)(p1 & 0xffff))) * inv);
            v[3] = f2bf((fs * o[4 * j + 3] + bf2f((unsigned short)(p1 >> 16))) * inv);
            *reinterpret_cast<u16x4*>(&xp[obase + j * 4]) = v;
        }
    }
}

// ---------------------------------------------------------------------------
// Pooling attention: block = (h, btl), 320 threads = 5 waves.
// Wave w handles key tiles {w, w+5} of 10 (32 keys each) with private online
// softmax; partials merged via LDS. K/V head-slices staged bf16->f32 in LDS.
// ---------------------------------------------------------------------------
__global__ __launch_bounds__(320)
void poolattn3_kernel(const unsigned short* __restrict__ kk,
                      const unsigned short* __restrict__ vv,
                      const float* __restrict__ qq, float* __restrict__ opool, int c0)
{
    __shared__ float ubuf[10560];      // union: K/V slots (w*2048) | sco (w*2112+q*33+d)
    __shared__ float scm[320], scl[320];
    const int tid = threadIdx.x;
    const int w = tid >> 6, lane = tid & 63;
    const int h = blockIdx.x, btl = blockIdx.y;
    const int bt = c0 + btl;
    float* Kf = ubuf + w * 2048;
    float* Vf = Kf + 1024;

    float qreg[32];
    const size_t qbase = (size_t)(bt * 64 + lane) * 192 + h * 32;
#pragma unroll
    for (int j = 0; j < 8; j++) {
        float4 v = *reinterpret_cast<const float4*>(&qq[qbase + j * 4]);
        qreg[4 * j] = v.x; qreg[4 * j + 1] = v.y;
        qreg[4 * j + 2] = v.z; qreg[4 * j + 3] = v.w;
    }
    const float scale = 0.17677669529663688110f;
    float mrun = -3.0e38f, lrun = 0.f;
    float o[32];
#pragma unroll
    for (int d = 0; d < 32; d++) o[d] = 0.f;

#pragma unroll
    for (int it = 0; it < 2; it++) {
        const int tt = w + it * 5;
        const unsigned short* ks = kk + (size_t)(btl * 320 + tt * 32) * 192 + h * 32;
        const unsigned short* vs = vv + (size_t)(btl * 320 + tt * 32) * 192 + h * 32;
#pragma unroll
        for (int ci = 0; ci < 2; ci++) {
            int idx = lane + ci * 64;          // 0..127
            int j = idx >> 2, q4 = (idx & 3) * 8;
            s16x8 kv8 = *reinterpret_cast<const s16x8*>(&ks[j * 192 + q4]);
            s16x8 vv8 = *reinterpret_cast<const s16x8*>(&vs[j * 192 + q4]);
            f32x4 lo, hi, vlo, vhi;
#pragma unroll
            for (int e = 0; e < 4; e++) {
                lo[e] = bf2f((unsigned short)kv8[e]);
                hi[e] = bf2f((unsigned short)kv8[e + 4]);
                vlo[e] = bf2f((unsigned short)vv8[e]);
                vhi[e] = bf2f((unsigned short)vv8[e + 4]);
            }
            *reinterpret_cast<f32x4*>(Kf + j * 32 + q4) = lo;
            *reinterpret_cast<f32x4*>(Kf + j * 32 + q4 + 4) = hi;
            *reinterpret_cast<f32x4*>(Vf + j * 32 + q4) = vlo;
            *reinterpret_cast<f32x4*>(Vf + j * 32 + q4 + 4) = vhi;
        }
        float s[32];
#pragma unroll
        for (int j = 0; j < 32; j++) {
            const float4* kr = reinterpret_cast<const float4*>(Kf + j * 32);
            float d0 = 0, d1 = 0, d2 = 0, d3 = 0;
#pragma unroll
            for (int q8 = 0; q8 < 8; q8++) {
                float4 k4 = kr[q8];
                d0 += qreg[q8 * 4] * k4.x;
                d1 += qreg[q8 * 4 + 1] * k4.y;
                d2 += qreg[q8 * 4 + 2] * k4.z;
                d3 += qreg[q8 * 4 + 3] * k4.w;
            }
            s[j] = (d0 + d1 + d2 + d3) * scale;
        }
        float mt = s[0];
#pragma unroll
        for (int j = 1; j < 32; j++) mt = fmaxf(mt, s[j]);
        float mnew = fmaxf(mrun, mt);
        float fct = __expf(mrun - mnew);
        lrun *= fct;
#pragma unroll
        for (int d = 0; d < 32; d++) o[d] *= fct;
#pragma unroll
        for (int j = 0; j < 32; j++) { float p = __expf(s[j] - mnew); lrun += p; s[j] = p; }
#pragma unroll
        for (int j = 0; j < 32; j++) {
            float p = s[j];
            const float4* vr = reinterpret_cast<const float4*>(Vf + j * 32);
#pragma unroll
            for (int d8 = 0; d8 < 8; d8++) {
                float4 v4 = vr[d8];
                o[d8 * 4] += p * v4.x; o[d8 * 4 + 1] += p * v4.y;
                o[d8 * 4 + 2] += p * v4.z; o[d8 * 4 + 3] += p * v4.w;
            }
        }
        mrun = mnew;
    }
    __syncthreads();                 // everyone done with K/V region
    scm[w * 64 + lane] = mrun;
    scl[w * 64 + lane] = lrun;
#pragma unroll
    for (int d = 0; d < 32; d++) ubuf[w * 2112 + lane * 33 + d] = o[d];
    __syncthreads();

    if (w == 0) {
        float m5 = scm[lane];
#pragma unroll
        for (int ww = 1; ww < 5; ww++) m5 = fmaxf(m5, scm[ww * 64 + lane]);
        float den = 0.f;
        float od[32];
#pragma unroll
        for (int d = 0; d < 32; d++) od[d] = 0.f;
#pragma unroll
        for (int ww = 0; ww < 5; ww++) {
            float f = __expf(scm[ww * 64 + lane] - m5);
            den += f * scl[ww * 64 + lane];
            const float* src = ubuf + ww * 2112 + lane * 33;
#pragma unroll
            for (int d = 0; d < 32; d++) od[d] += f * src[d];
        }
        const float inv = 1.f / den;
        const size_t ob = (size_t)(bt * 64 + lane) * 192 + h * 32;
#pragma unroll
        for (int j = 0; j < 8; j++) {
            float4 v;
            v.x = od[4 * j] * inv; v.y = od[4 * j + 1] * inv;
            v.z = od[4 * j + 2] * inv; v.w = od[4 * j + 3] * inv;
            *reinterpret_cast<float4*>(&opool[ob + j * 4]) = v;
        }
    }
}

extern "C" void kernel_launch(void* const* d_in, const int* in_sizes, int n_in,
                              void* d_out, int out_size, void* d_ws, size_t ws_size,
                              hipStream_t stream) {
    (void)in_sizes; (void)n_in; (void)out_size; (void)ws_size;
    const float* x      = (const float*)d_in[0];
    const float* x_kv   = (const float*)d_in[1];
    const float* mask   = (const float*)d_in[2];
    const float* rpbt   = (const float*)d_in[3];
    const float* q_w    = (const float*)d_in[4];
    const float* q_b    = (const float*)d_in[5];
    const float* kv_w   = (const float*)d_in[6];
    const float* kv_b   = (const float*)d_in[7];
    const float* pos    = (const float*)d_in[8];
    const float* pq_w   = (const float*)d_in[9];
    const float* pq_b   = (const float*)d_in[10];
    const float* pk_w   = (const float*)d_in[11];
    const float* pk_b   = (const float*)d_in[12];
    const float* pv_w   = (const float*)d_in[13];
    const float* pv_b   = (const float*)d_in[14];
    const float* po_w   = (const float*)d_in[15];
    const float* po_b   = (const float*)d_in[16];
    const float* proj_w = (const float*)d_in[17];
    const float* proj_b = (const float*)d_in[18];
    float* out = (float*)d_out;
    char* ws = (char*)d_ws;

    float*          qbuf = (float*)(ws);                       // 24 MB
    unsigned short* xp   = (unsigned short*)(ws + 25165824u);  // 48 MB bf16
    unsigned short* kbuf = (unsigned short*)(ws + 75497472u);  // 12 MB bf16
    unsigned short* vbuf = (unsigned short*)(ws + 88080384u);  // 12 MB bf16
    float*          qq   = qbuf;
    unsigned short* kkc  = (unsigned short*)(ws + 75497472u);  // 31.5 MB / chunk
    unsigned short* vvc  = (unsigned short*)(ws + 106954752u); // 31.5 MB / chunk
    float*          opo  = (float*)(ws + 75497472u);           // after pooling
    float*          opool = out;                               // d_out as scratch

    dim3 blk(256);
    // q = x @ q_w^T + q_b
    mgemm_kernel<0, 0, 0><<<dim3(256, 2), blk, 0, stream>>>(
        x, nullptr, nullptr, q_w, nullptr, q_b, nullptr, qbuf, nullptr, 0);
    // k,v = x_kv @ kv_w^T + kv_b  (split at oc 192, bf16 out)
    mgemm_kernel<0, 2, 1><<<dim3(256, 4), blk, 0, stream>>>(
        x_kv, nullptr, nullptr, kv_w, nullptr, kv_b, nullptr, kbuf, vbuf, 0);
    winattn_kernel<<<2048, 768, 0, stream>>>(qbuf, kbuf, vbuf, mask, rpbt, xp);
    // qq = (mean_m xp + pos) @ pq_w^T + pq_b
    mgemm_kernel<1, 0, 0><<<dim3(256, 2), blk, 0, stream>>>(
        nullptr, xp, pos, pq_w, nullptr, pq_b, nullptr, qq, nullptr, 0);
    // pooling in 2 chunks of 256 bt
    for (int c0 = 0; c0 < 512; c0 += 256) {
        mgemm_kernel<2, 3, 1><<<dim3(640, 4), blk, 0, stream>>>(
            nullptr, xp, pos, pk_w, pv_w, pk_b, pv_b, kkc, vvc, c0);
        poolattn3_kernel<<<dim3(6, 256), 320, 0, stream>>>(kkc, vvc, qq, opool, c0);
    }
    // opo = gelu(opool @ po_w^T + po_b); out = opo @ proj_w^T + proj_b
    mgemm_kernel<0, 1, 0><<<dim3(256, 2), blk, 0, stream>>>(
        opool, nullptr, nullptr, po_w, nullptr, po_b, nullptr, opo, nullptr, 0);
    mgemm_kernel<0, 0, 0><<<dim3(256, 2), blk, 0, stream>>>(
        opo, nullptr, nullptr, proj_w, nullptr, proj_b, nullptr, out, nullptr, 0);
}